// Round 9
// baseline (180.951 us; speedup 1.0000x reference)
//
#include <hip/hip_runtime.h>

// Problem constants
#define M_TOKENS 65536      // 8 * 8192
#define HID      256
#define KCODES   512

#define IND_OFF  (M_TOKENS * HID)          // 16777216
#define LOSS_OFF (IND_OFF + M_TOKENS)      // 16842752

// Flag threshold: any token whose top-2 score gap is below this gets exact
// re-scoring with the emulated reference-f32 quantization pipeline.
// bf16-split GEMM worst-case score error ~5e-6 << TAU; grid 2*3.05e-5 < TAU.
#define TAU      1.5e-4f

// ws layout (fast path):
//   [0:8) double loss | [8:12) int cnt | [16:2064) c2[512]
//   [4096 : +256K) B_hi fragments | [266240 : +256K) B_lo | [528384 : +32K) list
#define WS_C2_OFF        16
#define WS_BHI_OFF       4096
#define WS_BLO_OFF       (4096 + 262144)
#define WS_LIST_OFF_FAST (4096 + 524288)
#define WS_LIST_OFF_SLOW 4096
#define WS_MIN_FAST      (WS_LIST_OFF_FAST + 8192 * 4)

typedef __attribute__((ext_vector_type(8))) short  short8;   // 8 bf16
typedef __attribute__((ext_vector_type(4))) float  f32x4;

__device__ inline unsigned short f2bf(float f) {             // RNE f32->bf16
    unsigned u = __float_as_uint(f);
    u += 0x7FFF + ((u >> 16) & 1);
    return (unsigned short)(u >> 16);
}
__device__ inline float bf2f(unsigned short h) {
    return __uint_as_float(((unsigned)h) << 16);
}

// ---------------------------------------------------------------------------
// prep: blocks 0..63 swizzle codebook into MFMA B-fragment order (bf16 hi/lo);
//       blocks 64..65 compute c2[k] (f64) and zero the accumulators.
// Fragment (nb, kb): lane l, elem j -> code = nb*16 + (l&15),
//                                      k = kb*32 + (l>>4)*8 + j.
// ---------------------------------------------------------------------------
__global__ __launch_bounds__(256) void vq_prep(
    const float* __restrict__ cb,
    unsigned short* __restrict__ Bhi, unsigned short* __restrict__ Blo,
    float* __restrict__ c2, double* __restrict__ acc, int* __restrict__ cnt) {
    int b = blockIdx.x;
    if (b < 64) {
        int g = b * 256 + threadIdx.x;   // 0..16383 = frag*64 + lane
        int frag = g >> 6, lane = g & 63;
        int nb = frag >> 3, kb = frag & 7;
        int code = nb * 16 + (lane & 15);
        int kk = kb * 32 + (lane >> 4) * 8;
        const float4* s4 = reinterpret_cast<const float4*>(cb + code * HID + kk);
        float4 v0 = s4[0], v1 = s4[1];
        float f[8] = {v0.x, v0.y, v0.z, v0.w, v1.x, v1.y, v1.z, v1.w};
        short8 vh, vl;
        #pragma unroll
        for (int j = 0; j < 8; ++j) {
            unsigned short h = f2bf(f[j]);
            vh[j] = (short)h;
            vl[j] = (short)f2bf(f[j] - bf2f(h));
        }
        *reinterpret_cast<short8*>(Bhi + (size_t)g * 8) = vh;
        *reinterpret_cast<short8*>(Blo + (size_t)g * 8) = vl;
    } else {
        if (b == 64 && threadIdx.x == 0) { *acc = 0.0; *cnt = 0; }
        int k = (b - 64) * 256 + threadIdx.x;   // 0..511
        const float* row = cb + k * HID;
        double s = 0.0;
        for (int i = 0; i < HID; ++i) {
            double v = (double)row[i];
            s = fma(v, v, s);
        }
        c2[k] = (float)s;
    }
}

// ---------------------------------------------------------------------------
// main MFMA kernel: bf16-split cross-term + top-2 argmin + gather + loss.
// 256 threads = 4 waves; wave owns 32 tokens (2 M-frags). Grid = 512 blocks.
// B staged per 16-code chunk into TRIPLE-buffered LDS via global_load_lds;
// counted-vmcnt pipeline: stage chunk nb+2 each iter, raw s_barrier preceded
// by s_waitcnt vmcnt(4) (never 0) so 4 loads/wave stay in flight across the
// barrier. No VMEM loads inside the loop except stages (c2 is in LDS).
// Loss algebraic (no z re-read).
// ---------------------------------------------------------------------------
__global__ __launch_bounds__(256, 2) void vq_main_mfma(
    const float* __restrict__ z, const float* __restrict__ cb,
    const float* __restrict__ c2g,
    const unsigned short* __restrict__ Bhi,
    const unsigned short* __restrict__ Blo,
    float* __restrict__ out, double* __restrict__ loss_acc,
    int* __restrict__ cnt, int* __restrict__ list, int cap) {

    __shared__ short8 ldsB[3][16][64];   // 3 bufs x 16 KB = 48 KB
    __shared__ float  lds_c2[KCODES];    // 2 KB

    const int tid  = threadIdx.x;
    const int wid  = tid >> 6;
    const int lane = tid & 63;
    const int q    = lane >> 4;
    const int tokW = blockIdx.x * 128 + wid * 32;   // wave's first token

    const float4* z4  = reinterpret_cast<const float4*>(z);
    const float4* cb4 = reinterpret_cast<const float4*>(cb);

    // stage c2 into LDS (plain loads; their vmcnt drains before the ds_write,
    // which happens BEFORE any pipeline stages are issued below)
    lds_c2[tid]       = c2g[tid];
    lds_c2[tid + 256] = c2g[tid + 256];

    // stage one 16-frag chunk (16 KB): wave wid loads frags wid*4..wid*4+3
    // (lds dest: wave-uniform base + lane*16 -- required by global_load_lds)
#define STAGE(nbv, bufv) do {                                                  \
        _Pragma("unroll")                                                      \
        for (int j = 0; j < 4; ++j) {                                          \
            int f_  = (wid << 2) | j;                                          \
            int kb_ = f_ & 7;                                                  \
            const unsigned short* src_ =                                       \
                ((f_ < 8) ? Bhi : Blo) +                                       \
                (((size_t)((nbv) * 8 + kb_) * 64 + lane) << 3);                \
            __builtin_amdgcn_global_load_lds(                                  \
                (const __attribute__((address_space(1))) void*)src_,           \
                (__attribute__((address_space(3))) void*)&ldsB[bufv][f_][0],   \
                16, 0, 0);                                                     \
        }                                                                      \
    } while (0)

    // ---- load wave's 32 z rows as A fragments (bf16 hi/lo) + z2 ----
    // A frag (mf,kb): lane holds token tokW+mf*16+(l&15), k = kb*32+(l>>4)*8+j
    short8 ah[2][8], al[2][8];
    float sq[2];
    #pragma unroll
    for (int mf = 0; mf < 2; ++mf) {
        int token = tokW + mf * 16 + (lane & 15);
        const float4* zr = z4 + (size_t)token * 64 + q * 2;
        float s = 0.f;
        #pragma unroll
        for (int kb = 0; kb < 8; ++kb) {
            float4 v0 = zr[kb * 8];
            float4 v1 = zr[kb * 8 + 1];
            float f[8] = {v0.x, v0.y, v0.z, v0.w, v1.x, v1.y, v1.z, v1.w};
            short8 vh, vl;
            #pragma unroll
            for (int j = 0; j < 8; ++j) {
                unsigned short h = f2bf(f[j]);
                vh[j] = (short)h;
                vl[j] = (short)f2bf(f[j] - bf2f(h));
                s = fmaf(f[j], f[j], s);
            }
            ah[mf][kb] = vh;
            al[mf][kb] = vl;
        }
        // z2 of token tokW+mf*16+(lane&15), replicated across q-groups
        s += __shfl_xor(s, 16, 64);
        s += __shfl_xor(s, 32, 64);
        sq[mf] = s;
    }

    // prologue: prefetch chunks 0 and 1 (8 loads/wave in flight);
    // lgkmcnt(0) makes this wave's lds_c2 ds_writes visible before barrier.
    STAGE(0, 0);
    STAGE(1, 1);
    asm volatile("s_waitcnt lgkmcnt(0)" ::: "memory");

    // per-lane running top-2 for 2 mfrags x 4 rows
    float b1[2][4], b2[2][4];
    int   i1[2][4];
    #pragma unroll
    for (int mf = 0; mf < 2; ++mf)
        #pragma unroll
        for (int r = 0; r < 4; ++r) { b1[mf][r] = 3.4e38f; b2[mf][r] = 3.4e38f; i1[mf][r] = 0; }

    // ---- main loop over 32 code-chunks of 16; triple-buffer, vmcnt(4) ----
    int bcur = 0, bnx2 = 2;
    for (int nb = 0; nb < 32; ++nb) {
        // chunk nb's 4 loads landed when <=4 remain (chunk nb+1's stay out).
        // Every wave does this BEFORE the barrier, so at barrier-exit all
        // waves' chunk-nb fragments are in LDS.
        asm volatile("s_waitcnt vmcnt(4)" ::: "memory");
        __builtin_amdgcn_s_barrier();
        __builtin_amdgcn_sched_barrier(0);

        // stage chunk nb+2 into buffer of chunk nb-1 (dead: the barrier above
        // followed every wave's compute(nb-1)). nb=30/31 wrap to dummy
        // re-stages of chunks 0/1 -> keeps vmcnt count uniform, no harm.
        STAGE((nb + 2) & 31, bnx2);

        f32x4 a0 = {0.f, 0.f, 0.f, 0.f};
        f32x4 a1 = {0.f, 0.f, 0.f, 0.f};
        #pragma unroll
        for (int kb = 0; kb < 8; ++kb) {
            short8 vbh = ldsB[bcur][kb][lane];
            short8 vbl = ldsB[bcur][8 + kb][lane];
            a0 = __builtin_amdgcn_mfma_f32_16x16x32_bf16(ah[0][kb], vbh, a0, 0, 0, 0);
            a1 = __builtin_amdgcn_mfma_f32_16x16x32_bf16(ah[1][kb], vbh, a1, 0, 0, 0);
            a0 = __builtin_amdgcn_mfma_f32_16x16x32_bf16(al[0][kb], vbh, a0, 0, 0, 0);
            a1 = __builtin_amdgcn_mfma_f32_16x16x32_bf16(al[1][kb], vbh, a1, 0, 0, 0);
            a0 = __builtin_amdgcn_mfma_f32_16x16x32_bf16(ah[0][kb], vbl, a0, 0, 0, 0);
            a1 = __builtin_amdgcn_mfma_f32_16x16x32_bf16(ah[1][kb], vbl, a1, 0, 0, 0);
        }
        int code = nb * 16 + (lane & 15);
        float c2v = lds_c2[code];
        #pragma unroll
        for (int r = 0; r < 4; ++r) {
            float s0 = fmaf(-2.f, a0[r], c2v);   // c2 - 2*cross
            if (s0 < b1[0][r]) { b2[0][r] = b1[0][r]; b1[0][r] = s0; i1[0][r] = code; }
            else if (s0 < b2[0][r]) b2[0][r] = s0;
            float s1 = fmaf(-2.f, a1[r], c2v);
            if (s1 < b1[1][r]) { b2[1][r] = b1[1][r]; b1[1][r] = s1; i1[1][r] = code; }
            else if (s1 < b2[1][r]) b2[1][r] = s1;
        }
        bcur = (bcur == 2) ? 0 : bcur + 1;
        bnx2 = (bnx2 == 2) ? 0 : bnx2 + 1;
    }
#undef STAGE

    // ---- merge top-2 across the 16 lanes of each row group ----
    #pragma unroll
    for (int st = 1; st <= 8; st <<= 1) {
        #pragma unroll
        for (int mf = 0; mf < 2; ++mf)
            #pragma unroll
            for (int r = 0; r < 4; ++r) {
                float ob1 = __shfl_xor(b1[mf][r], st, 64);
                int   oi1 = __shfl_xor(i1[mf][r], st, 64);
                float ob2 = __shfl_xor(b2[mf][r], st, 64);
                if (ob1 < b1[mf][r] || (ob1 == b1[mf][r] && oi1 < i1[mf][r])) {
                    b2[mf][r] = fminf(b1[mf][r], ob2);
                    b1[mf][r] = ob1;
                    i1[mf][r] = oi1;
                } else {
                    b2[mf][r] = fminf(b2[mf][r], ob1);
                }
            }
    }

    // ---- indices + ambiguity flags ----
    if ((lane & 15) == 0) {
        #pragma unroll
        for (int mf = 0; mf < 2; ++mf) {
            float4 iv;
            #pragma unroll
            for (int r = 0; r < 4; ++r) {
                ((float*)&iv)[r] = (float)i1[mf][r];
                if (b2[mf][r] - b1[mf][r] <= TAU) {
                    int pos = atomicAdd(cnt, 1);
                    if (pos < cap) list[pos] = tokW + mf * 16 + q * 4 + r;
                }
            }
            *reinterpret_cast<float4*>(out + IND_OFF + tokW + mf * 16 + q * 4) = iv;
        }
    }

    // ---- loss: ||zq-z||^2 = z2 + (c2_best - 2 cross_best) = z2 + b1 ----
    double lsum = 0.0;
    #pragma unroll
    for (int mf = 0; mf < 2; ++mf)
        #pragma unroll
        for (int r = 0; r < 4; ++r) {
            float z2r = __shfl(sq[mf], (lane & 48) | (q * 4 + r), 64);
            if ((lane & 15) == 0) lsum += (double)z2r + (double)b1[mf][r];
        }
    lsum += __shfl_xor(lsum, 16, 64);
    lsum += __shfl_xor(lsum, 32, 64);
    if (lane == 0) atomicAdd(loss_acc, lsum);

    // ---- gather z_q rows from codebook, write out ----
    float4* out4 = reinterpret_cast<float4*>(out);
    #pragma unroll
    for (int tt = 0; tt < 32; ++tt) {
        int code = __shfl(i1[tt >> 4][tt & 3], ((tt >> 2) & 3) * 16, 64);
        float4 cv = cb4[(size_t)code * 64 + lane];
        out4[(size_t)(tokW + tt) * 64 + lane] = cv;
    }
}

// ---------------------------------------------------------------------------
// FALLBACK (small ws): round-3 f32 VALU kernel, verified correct.
// ---------------------------------------------------------------------------
#define BM   128
#define NC   128
#define KS   32
#define PAD  33

__global__ void vq_init(const float* __restrict__ cb, float* __restrict__ c2,
                        double* __restrict__ acc, int* __restrict__ cnt) {
    int k = threadIdx.x;
    if (k == 0) { *acc = 0.0; *cnt = 0; }
    const float* row = cb + k * HID;
    double s = 0.0;
    for (int i = 0; i < HID; ++i) {
        double v = (double)row[i];
        s = fma(v, v, s);
    }
    c2[k] = (float)s;
}

__global__ __launch_bounds__(256, 2) void vq_main_f32(
    const float* __restrict__ z, const float* __restrict__ cb,
    const float* __restrict__ c2g, float* __restrict__ out,
    double* __restrict__ loss_acc, int* __restrict__ cnt,
    int* __restrict__ list, int cap) {

    __shared__ float smem[(BM + NC) * PAD];
    float* zs = smem;
    float* cs = smem + BM * PAD;

    const int tid = threadIdx.x;
    const int tx = tid & 15;
    const int ty = tid >> 4;
    const int tokBase = blockIdx.x * BM;

    const float4* z4g  = reinterpret_cast<const float4*>(z);
    const float4* cb4g = reinterpret_cast<const float4*>(cb);

    float bs[8], bs2[8];
    int   bi[8];
    #pragma unroll
    for (int m = 0; m < 8; ++m) { bs[m] = 3.4e38f; bs2[m] = 3.4e38f; bi[m] = 0; }

    for (int chunk = 0; chunk < KCODES / NC; ++chunk) {
        float acc[8][8];
        #pragma unroll
        for (int m = 0; m < 8; ++m)
            #pragma unroll
            for (int n = 0; n < 8; ++n) acc[m][n] = 0.f;

        for (int ks = 0; ks < HID / KS; ++ks) {
            __syncthreads();
            #pragma unroll
            for (int i = 0; i < 4; ++i) {
                int f   = tid + i * 256;
                int row = f >> 3;
                int k4  = f & 7;
                float4 zv = z4g[(tokBase + row) * (HID / 4) + ks * (KS / 4) + k4];
                int b = row * PAD + k4 * 4;
                zs[b + 0] = zv.x; zs[b + 1] = zv.y; zs[b + 2] = zv.z; zs[b + 3] = zv.w;
                float4 cv = cb4g[(chunk * NC + row) * (HID / 4) + ks * (KS / 4) + k4];
                cs[b + 0] = cv.x; cs[b + 1] = cv.y; cs[b + 2] = cv.z; cs[b + 3] = cv.w;
            }
            __syncthreads();

            #pragma unroll 2
            for (int k = 0; k < KS; ++k) {
                float zf[8], cf[8];
                #pragma unroll
                for (int m = 0; m < 8; ++m) zf[m] = zs[(ty * 8 + m) * PAD + k];
                #pragma unroll
                for (int n = 0; n < 8; ++n) cf[n] = cs[(tx * 8 + n) * PAD + k];
                #pragma unroll
                for (int m = 0; m < 8; ++m)
                    #pragma unroll
                    for (int n = 0; n < 8; ++n)
                        acc[m][n] = fmaf(zf[m], cf[n], acc[m][n]);
            }
        }

        #pragma unroll
        for (int n = 0; n < 8; ++n) {
            int code = chunk * NC + tx * 8 + n;
            float c2v = c2g[code];
            #pragma unroll
            for (int m = 0; m < 8; ++m) {
                float s = fmaf(-2.f, acc[m][n], c2v);
                if (s < bs[m]) { bs2[m] = bs[m]; bs[m] = s; bi[m] = code; }
                else if (s < bs2[m]) bs2[m] = s;
            }
        }
    }

    __syncthreads();
    float* rs   = smem;
    int*   ri   = reinterpret_cast<int*>(smem + BM * 16);
    float* rs2  = smem + BM * 32;
    int*   inds = reinterpret_cast<int*>(smem + BM * 48);
    float* wred = smem + BM * 48 + BM;

    #pragma unroll
    for (int m = 0; m < 8; ++m) {
        int tok = ty * 8 + m;
        rs [tok * 16 + tx] = bs[m];
        ri [tok * 16 + tx] = bi[m];
        rs2[tok * 16 + tx] = bs2[m];
    }
    __syncthreads();

    if (tid < BM) {
        float B1 = rs[tid * 16];
        int   I1 = ri[tid * 16];
        float B2 = rs2[tid * 16];
        for (int j = 1; j < 16; ++j) {
            float b1v = rs [tid * 16 + j];
            int   i1v = ri [tid * 16 + j];
            float b2v = rs2[tid * 16 + j];
            if (b1v < B1 || (b1v == B1 && i1v < I1)) {
                B2 = fminf(B1, b2v); B1 = b1v; I1 = i1v;
            } else {
                B2 = fminf(B2, b1v);
            }
        }
        inds[tid] = I1;
        out[IND_OFF + tokBase + tid] = (float)I1;
        if (B2 - B1 <= TAU) {
            int pos = atomicAdd(cnt, 1);
            if (pos < cap) list[pos] = tokBase + tid;
        }
    }
    __syncthreads();

    float loc = 0.f;
    float4* out4 = reinterpret_cast<float4*>(out);
    for (int it = 0; it < (BM * HID / 4) / 256; ++it) {
        int e4  = it * 256 + tid;
        int tok = e4 >> 6;
        int h4  = e4 & 63;
        int code = inds[tok];
        float4 cv = cb4g[code * 64 + h4];
        float4 zv = z4g[(tokBase + tok) * 64 + h4];
        out4[(tokBase + tok) * 64 + h4] = cv;
        float dx = cv.x - zv.x, dy = cv.y - zv.y;
        float dz = cv.z - zv.z, dw = cv.w - zv.w;
        loc = fmaf(dx, dx, loc);
        loc = fmaf(dy, dy, loc);
        loc = fmaf(dz, dz, loc);
        loc = fmaf(dw, dw, loc);
    }
    #pragma unroll
    for (int off = 32; off > 0; off >>= 1) loc += __shfl_xor(loc, off, 64);
    int wave = tid >> 6;
    if ((tid & 63) == 0) wred[wave] = loc;
    __syncthreads();
    if (tid == 0) {
        double t = (double)wred[0] + (double)wred[1] +
                   (double)wred[2] + (double)wred[3];
        atomicAdd(loss_acc, t);
    }
}

// ---------------------------------------------------------------------------
// refine: re-score flagged tokens with the EMULATED reference f32 pipeline:
//   D_k = fl32( fl32(z2 - fl32(2*cross_k)) + c2_k ),  argmin first-index.
// cross in f64 (any summation order: f64 error ~1e-13 << f32 ulp), computed
// with float4 loads + 8 independent partial chains for ILP.
// Also finalizes the loss output (block 0, thread 0).
// ---------------------------------------------------------------------------
__global__ __launch_bounds__(256) void vq_refine(
    const float* __restrict__ z, const float* __restrict__ cb,
    const float* __restrict__ c2g, const double* __restrict__ loss_acc,
    const int* __restrict__ cnt, const int* __restrict__ list,
    float* __restrict__ out, int cap) {

    if (blockIdx.x == 0 && threadIdx.x == 0)
        out[LOSS_OFF] = (float)(2.0 * (*loss_acc) / (double)(M_TOKENS * HID));

    __shared__ float  zrow[HID];
    __shared__ double red_d[256];
    __shared__ int    red_i[256];

    const int tid = threadIdx.x;
    int n = *cnt; if (n > cap) n = cap;

    for (int idx = blockIdx.x; idx < n; idx += gridDim.x) {
        int t = list[idx];
        float zi = z[t * HID + tid];
        zrow[tid] = zi;
        red_d[tid] = (double)zi * (double)zi;
        __syncthreads();
        for (int s = 128; s > 0; s >>= 1) {
            if (tid < s) red_d[tid] += red_d[tid + s];
            __syncthreads();
        }
        float z2f = (float)red_d[0];
        __syncthreads();

        // two codes per thread: k=tid and k=tid+256; 8 f64 chains of 64
        const float4* zr4 = reinterpret_cast<const float4*>(zrow);
        const float4* c0  = reinterpret_cast<const float4*>(cb + tid * HID);
        const float4* c1  = reinterpret_cast<const float4*>(cb + (tid + 256) * HID);
        double p00 = 0, p01 = 0, p02 = 0, p03 = 0;
        double p10 = 0, p11 = 0, p12 = 0, p13 = 0;
        #pragma unroll 4
        for (int i = 0; i < HID / 4; ++i) {
            float4 zv = zr4[i];
            float4 a = c0[i];
            float4 b = c1[i];
            p00 = fma((double)zv.x, (double)a.x, p00);
            p01 = fma((double)zv.y, (double)a.y, p01);
            p02 = fma((double)zv.z, (double)a.z, p02);
            p03 = fma((double)zv.w, (double)a.w, p03);
            p10 = fma((double)zv.x, (double)b.x, p10);
            p11 = fma((double)zv.y, (double)b.y, p11);
            p12 = fma((double)zv.z, (double)b.z, p12);
            p13 = fma((double)zv.w, (double)b.w, p13);
        }
        double bestD = 1e300; int bestK = 1 << 30;
        #pragma unroll
        for (int c = 0; c < 2; ++c) {
            int k = tid + c * 256;
            double accd = (c == 0) ? ((p00 + p01) + (p02 + p03))
                                   : ((p10 + p11) + (p12 + p13));
            float cross32 = (float)accd;                      // fl32(cross)
            float u = 2.0f * cross32;                          // exact
            float tq = (float)((double)z2f - (double)u);       // fl32(z2-u)
            double v = (double)tq + (double)c2g[k];
            float D = (float)v;                                // fl32(t+c2)
            double Dd = (double)D;
            if (Dd < bestD || (Dd == bestD && k < bestK)) { bestD = Dd; bestK = k; }
        }
        red_d[tid] = bestD; red_i[tid] = bestK;
        __syncthreads();
        for (int s = 128; s > 0; s >>= 1) {
            if (tid < s) {
                double d2 = red_d[tid + s]; int i2 = red_i[tid + s];
                if (d2 < red_d[tid] || (d2 == red_d[tid] && i2 < red_i[tid])) {
                    red_d[tid] = d2; red_i[tid] = i2;
                }
            }
            __syncthreads();
        }
        int best = red_i[0];
        if (tid == 0) out[IND_OFF + t] = (float)best;
        out[t * HID + tid] = cb[best * HID + tid];
        __syncthreads();
    }
}

extern "C" void kernel_launch(void* const* d_in, const int* in_sizes, int n_in,
                              void* d_out, int out_size, void* d_ws, size_t ws_size,
                              hipStream_t stream) {
    const float* z  = (const float*)d_in[0];
    const float* cb = (const float*)d_in[1];
    float* out = (float*)d_out;
    double* acc = (double*)d_ws;
    int*  cnt = (int*)((char*)d_ws + 8);
    float* c2 = (float*)((char*)d_ws + WS_C2_OFF);

    if (ws_size >= WS_MIN_FAST) {
        unsigned short* Bhi = (unsigned short*)((char*)d_ws + WS_BHI_OFF);
        unsigned short* Blo = (unsigned short*)((char*)d_ws + WS_BLO_OFF);
        int* list = (int*)((char*)d_ws + WS_LIST_OFF_FAST);
        int cap = 8192;
        vq_prep<<<66, 256, 0, stream>>>(cb, Bhi, Blo, c2, acc, cnt);
        vq_main_mfma<<<M_TOKENS / 128, 256, 0, stream>>>(
            z, cb, c2, Bhi, Blo, out, acc, cnt, list, cap);
        vq_refine<<<512, 256, 0, stream>>>(z, cb, c2, acc, cnt, list, out, cap);
    } else {
        int* list = (int*)((char*)d_ws + WS_LIST_OFF_SLOW);
        int cap = 0;
        if (ws_size > WS_LIST_OFF_SLOW + 16) {
            size_t avail = (ws_size - WS_LIST_OFF_SLOW) / 4;
            cap = (avail > 8192) ? 8192 : (int)avail;
        }
        vq_init<<<1, 512, 0, stream>>>(cb, c2, acc, cnt);
        vq_main_f32<<<M_TOKENS / BM, 256, 0, stream>>>(
            z, cb, c2, out, acc, cnt, list, cap);
        vq_refine<<<512, 256, 0, stream>>>(z, cb, c2, acc, cnt, list, out, cap);
    }
}

// Round 10
// 176.431 us; speedup vs baseline: 1.0256x; 1.0256x over previous
//
#include <hip/hip_runtime.h>

// Problem constants
#define M_TOKENS 65536      // 8 * 8192
#define HID      256
#define KCODES   512

#define IND_OFF  (M_TOKENS * HID)          // 16777216
#define LOSS_OFF (IND_OFF + M_TOKENS)      // 16842752

// Flag threshold: any token whose top-2 score gap is below this gets exact
// re-scoring with the emulated reference-f32 quantization pipeline.
// bf16-split GEMM worst-case score error ~5e-6 << TAU; grid 2*3.05e-5 < TAU.
#define TAU      1.5e-4f

// ws layout (fast path):
//   [0:8) double loss | [8:12) int cnt | [16:2064) c2[512]
//   [4096 : +256K) B_hi fragments | [266240 : +256K) B_lo | [528384 : +32K) list
#define WS_C2_OFF        16
#define WS_BHI_OFF       4096
#define WS_BLO_OFF       (4096 + 262144)
#define WS_LIST_OFF_FAST (4096 + 524288)
#define WS_LIST_OFF_SLOW 4096
#define WS_MIN_FAST      (WS_LIST_OFF_FAST + 8192 * 4)

typedef __attribute__((ext_vector_type(8))) short  short8;   // 8 bf16
typedef __attribute__((ext_vector_type(4))) float  f32x4;

__device__ inline unsigned short f2bf(float f) {             // RNE f32->bf16
    unsigned u = __float_as_uint(f);
    u += 0x7FFF + ((u >> 16) & 1);
    return (unsigned short)(u >> 16);
}
__device__ inline float bf2f(unsigned short h) {
    return __uint_as_float(((unsigned)h) << 16);
}

// ---------------------------------------------------------------------------
// prep: blocks 0..63 swizzle codebook into MFMA B-fragment order (bf16 hi/lo);
//       blocks 64..65 compute c2[k] (f64) and zero the accumulators.
// Fragment (nb, kb): lane l, elem j -> code = nb*16 + (l&15),
//                                      k = kb*32 + (l>>4)*8 + j.
// ---------------------------------------------------------------------------
__global__ __launch_bounds__(256) void vq_prep(
    const float* __restrict__ cb,
    unsigned short* __restrict__ Bhi, unsigned short* __restrict__ Blo,
    float* __restrict__ c2, double* __restrict__ acc, int* __restrict__ cnt) {
    int b = blockIdx.x;
    if (b < 64) {
        int g = b * 256 + threadIdx.x;   // 0..16383 = frag*64 + lane
        int frag = g >> 6, lane = g & 63;
        int nb = frag >> 3, kb = frag & 7;
        int code = nb * 16 + (lane & 15);
        int kk = kb * 32 + (lane >> 4) * 8;
        const float4* s4 = reinterpret_cast<const float4*>(cb + code * HID + kk);
        float4 v0 = s4[0], v1 = s4[1];
        float f[8] = {v0.x, v0.y, v0.z, v0.w, v1.x, v1.y, v1.z, v1.w};
        short8 vh, vl;
        #pragma unroll
        for (int j = 0; j < 8; ++j) {
            unsigned short h = f2bf(f[j]);
            vh[j] = (short)h;
            vl[j] = (short)f2bf(f[j] - bf2f(h));
        }
        *reinterpret_cast<short8*>(Bhi + (size_t)g * 8) = vh;
        *reinterpret_cast<short8*>(Blo + (size_t)g * 8) = vl;
    } else {
        if (b == 64 && threadIdx.x == 0) { *acc = 0.0; *cnt = 0; }
        int k = (b - 64) * 256 + threadIdx.x;   // 0..511
        const float* row = cb + k * HID;
        double s = 0.0;
        for (int i = 0; i < HID; ++i) {
            double v = (double)row[i];
            s = fma(v, v, s);
        }
        c2[k] = (float)s;
    }
}

// ---------------------------------------------------------------------------
// main MFMA kernel: bf16-split cross-term + top-2 argmin + gather + loss.
// 256 threads = 4 waves; wave owns 32 tokens (2 M-frags). Grid = 512 blocks
// (2 blocks/CU). BK=32 codes per phase (16 phases, 16 barriers): per phase
// each wave stages 8 frags (global_load_lds w16) into the double-buffered
// 32KB LDS chunk, then runs 2 independent 16-code sub-chunks (96 MFMAs, 4
// accumulator chains) -- long runs between barriers for compiler pipelining.
// s_setprio(1) around MFMA clusters (2 independent blocks/CU drift). Loss
// algebraic (no z re-read).
// ---------------------------------------------------------------------------
__global__ __launch_bounds__(256, 2) void vq_main_mfma(
    const float* __restrict__ z, const float* __restrict__ cb,
    const float* __restrict__ c2g,
    const unsigned short* __restrict__ Bhi,
    const unsigned short* __restrict__ Blo,
    float* __restrict__ out, double* __restrict__ loss_acc,
    int* __restrict__ cnt, int* __restrict__ list, int cap) {

    __shared__ short8 ldsB[2][32][64];   // 2 bufs x 32KB = 64 KB
    __shared__ float  lds_c2[KCODES];    // 2 KB

    const int tid  = threadIdx.x;
    const int wid  = tid >> 6;
    const int lane = tid & 63;
    const int q    = lane >> 4;
    const int tokW = blockIdx.x * 128 + wid * 32;   // wave's first token

    const float4* z4  = reinterpret_cast<const float4*>(z);
    const float4* cb4 = reinterpret_cast<const float4*>(cb);

    // stage c2 into LDS
    lds_c2[tid]       = c2g[tid];
    lds_c2[tid + 256] = c2g[tid + 256];

    // stage one 32-code phase (32 frag-slots of 1KB): wave wid stages slots
    // wid*8 .. wid*8+7.  Slot s: g=s>>4 (16-code group), t=s&15 (0..7 hi,
    // 8..15 lo), kb=t&7.  Source frag index nb = 2*phase+g.
#define STAGE(kv, bufv) do {                                                   \
        _Pragma("unroll")                                                      \
        for (int j = 0; j < 8; ++j) {                                          \
            int s_  = (wid << 3) | j;                                          \
            int g_  = s_ >> 4;                                                 \
            int t_  = s_ & 15;                                                 \
            int kb_ = t_ & 7;                                                  \
            const unsigned short* src_ =                                       \
                ((t_ < 8) ? Bhi : Blo) +                                       \
                (((size_t)((2 * (kv) + g_) * 8 + kb_) * 64 + lane) << 3);      \
            __builtin_amdgcn_global_load_lds(                                  \
                (const __attribute__((address_space(1))) void*)src_,           \
                (__attribute__((address_space(3))) void*)&ldsB[bufv][s_][0],   \
                16, 0, 0);                                                     \
        }                                                                      \
    } while (0)

    // issue phase-0 stage FIRST so it streams in under the A-load/convert
    STAGE(0, 0);

    // ---- load wave's 32 z rows as A fragments (bf16 hi/lo) + z2 ----
    // A frag (mf,kb): lane holds token tokW+mf*16+(l&15), k = kb*32+(l>>4)*8+j
    short8 ah[2][8], al[2][8];
    float sq[2];
    #pragma unroll
    for (int mf = 0; mf < 2; ++mf) {
        int token = tokW + mf * 16 + (lane & 15);
        const float4* zr = z4 + (size_t)token * 64 + q * 2;
        float s = 0.f;
        #pragma unroll
        for (int kb = 0; kb < 8; ++kb) {
            float4 v0 = zr[kb * 8];
            float4 v1 = zr[kb * 8 + 1];
            float f[8] = {v0.x, v0.y, v0.z, v0.w, v1.x, v1.y, v1.z, v1.w};
            short8 vh, vl;
            #pragma unroll
            for (int j = 0; j < 8; ++j) {
                unsigned short h = f2bf(f[j]);
                vh[j] = (short)h;
                vl[j] = (short)f2bf(f[j] - bf2f(h));
                s = fmaf(f[j], f[j], s);
            }
            ah[mf][kb] = vh;
            al[mf][kb] = vl;
        }
        // z2 of token tokW+mf*16+(lane&15), replicated across q-groups
        s += __shfl_xor(s, 16, 64);
        s += __shfl_xor(s, 32, 64);
        sq[mf] = s;
    }

    // per-lane running top-2 for 2 mfrags x 4 rows
    float b1[2][4], b2[2][4];
    int   i1[2][4];
    #pragma unroll
    for (int mf = 0; mf < 2; ++mf)
        #pragma unroll
        for (int r = 0; r < 4; ++r) { b1[mf][r] = 3.4e38f; b2[mf][r] = 3.4e38f; i1[mf][r] = 0; }

    // ---- main loop over 16 phases of 32 codes; dbuf, 1 barrier/phase ----
    #pragma unroll 2
    for (int k = 0; k < 16; ++k) {
        int buf = k & 1;
        __syncthreads();                    // phase-k data landed; buf^1 free
        if (k < 15) STAGE(k + 1, buf ^ 1);  // async prefetch under compute

        #pragma unroll
        for (int g = 0; g < 2; ++g) {
            f32x4 a0 = {0.f, 0.f, 0.f, 0.f};
            f32x4 a1 = {0.f, 0.f, 0.f, 0.f};
            __builtin_amdgcn_s_setprio(1);
            #pragma unroll
            for (int kb = 0; kb < 8; ++kb) {
                short8 vbh = ldsB[buf][g * 16 + kb][lane];
                short8 vbl = ldsB[buf][g * 16 + 8 + kb][lane];
                a0 = __builtin_amdgcn_mfma_f32_16x16x32_bf16(ah[0][kb], vbh, a0, 0, 0, 0);
                a1 = __builtin_amdgcn_mfma_f32_16x16x32_bf16(ah[1][kb], vbh, a1, 0, 0, 0);
                a0 = __builtin_amdgcn_mfma_f32_16x16x32_bf16(al[0][kb], vbh, a0, 0, 0, 0);
                a1 = __builtin_amdgcn_mfma_f32_16x16x32_bf16(al[1][kb], vbh, a1, 0, 0, 0);
                a0 = __builtin_amdgcn_mfma_f32_16x16x32_bf16(ah[0][kb], vbl, a0, 0, 0, 0);
                a1 = __builtin_amdgcn_mfma_f32_16x16x32_bf16(ah[1][kb], vbl, a1, 0, 0, 0);
            }
            __builtin_amdgcn_s_setprio(0);
            int code = (2 * k + g) * 16 + (lane & 15);
            float c2v = lds_c2[code];
            #pragma unroll
            for (int r = 0; r < 4; ++r) {
                float s0 = fmaf(-2.f, a0[r], c2v);   // c2 - 2*cross
                if (s0 < b1[0][r]) { b2[0][r] = b1[0][r]; b1[0][r] = s0; i1[0][r] = code; }
                else if (s0 < b2[0][r]) b2[0][r] = s0;
                float s1 = fmaf(-2.f, a1[r], c2v);
                if (s1 < b1[1][r]) { b2[1][r] = b1[1][r]; b1[1][r] = s1; i1[1][r] = code; }
                else if (s1 < b2[1][r]) b2[1][r] = s1;
            }
        }
    }
#undef STAGE

    // ---- merge top-2 across the 16 lanes of each row group ----
    #pragma unroll
    for (int st = 1; st <= 8; st <<= 1) {
        #pragma unroll
        for (int mf = 0; mf < 2; ++mf)
            #pragma unroll
            for (int r = 0; r < 4; ++r) {
                float ob1 = __shfl_xor(b1[mf][r], st, 64);
                int   oi1 = __shfl_xor(i1[mf][r], st, 64);
                float ob2 = __shfl_xor(b2[mf][r], st, 64);
                if (ob1 < b1[mf][r] || (ob1 == b1[mf][r] && oi1 < i1[mf][r])) {
                    b2[mf][r] = fminf(b1[mf][r], ob2);
                    b1[mf][r] = ob1;
                    i1[mf][r] = oi1;
                } else {
                    b2[mf][r] = fminf(b2[mf][r], ob1);
                }
            }
    }

    // ---- indices + ambiguity flags ----
    if ((lane & 15) == 0) {
        #pragma unroll
        for (int mf = 0; mf < 2; ++mf) {
            float4 iv;
            #pragma unroll
            for (int r = 0; r < 4; ++r) {
                ((float*)&iv)[r] = (float)i1[mf][r];
                if (b2[mf][r] - b1[mf][r] <= TAU) {
                    int pos = atomicAdd(cnt, 1);
                    if (pos < cap) list[pos] = tokW + mf * 16 + q * 4 + r;
                }
            }
            *reinterpret_cast<float4*>(out + IND_OFF + tokW + mf * 16 + q * 4) = iv;
        }
    }

    // ---- loss: ||zq-z||^2 = z2 + (c2_best - 2 cross_best) = z2 + b1 ----
    double lsum = 0.0;
    #pragma unroll
    for (int mf = 0; mf < 2; ++mf)
        #pragma unroll
        for (int r = 0; r < 4; ++r) {
            float z2r = __shfl(sq[mf], (lane & 48) | (q * 4 + r), 64);
            if ((lane & 15) == 0) lsum += (double)z2r + (double)b1[mf][r];
        }
    lsum += __shfl_xor(lsum, 16, 64);
    lsum += __shfl_xor(lsum, 32, 64);
    if (lane == 0) atomicAdd(loss_acc, lsum);

    // ---- gather z_q rows from codebook, write out ----
    float4* out4 = reinterpret_cast<float4*>(out);
    #pragma unroll
    for (int tt = 0; tt < 32; ++tt) {
        int code = __shfl(i1[tt >> 4][tt & 3], ((tt >> 2) & 3) * 16, 64);
        float4 cv = cb4[(size_t)code * 64 + lane];
        out4[(size_t)(tokW + tt) * 64 + lane] = cv;
    }
}

// ---------------------------------------------------------------------------
// FALLBACK (small ws): round-3 f32 VALU kernel, verified correct.
// ---------------------------------------------------------------------------
#define BM   128
#define NC   128
#define KS   32
#define PAD  33

__global__ void vq_init(const float* __restrict__ cb, float* __restrict__ c2,
                        double* __restrict__ acc, int* __restrict__ cnt) {
    int k = threadIdx.x;
    if (k == 0) { *acc = 0.0; *cnt = 0; }
    const float* row = cb + k * HID;
    double s = 0.0;
    for (int i = 0; i < HID; ++i) {
        double v = (double)row[i];
        s = fma(v, v, s);
    }
    c2[k] = (float)s;
}

__global__ __launch_bounds__(256, 2) void vq_main_f32(
    const float* __restrict__ z, const float* __restrict__ cb,
    const float* __restrict__ c2g, float* __restrict__ out,
    double* __restrict__ loss_acc, int* __restrict__ cnt,
    int* __restrict__ list, int cap) {

    __shared__ float smem[(BM + NC) * PAD];
    float* zs = smem;
    float* cs = smem + BM * PAD;

    const int tid = threadIdx.x;
    const int tx = tid & 15;
    const int ty = tid >> 4;
    const int tokBase = blockIdx.x * BM;

    const float4* z4g  = reinterpret_cast<const float4*>(z);
    const float4* cb4g = reinterpret_cast<const float4*>(cb);

    float bs[8], bs2[8];
    int   bi[8];
    #pragma unroll
    for (int m = 0; m < 8; ++m) { bs[m] = 3.4e38f; bs2[m] = 3.4e38f; bi[m] = 0; }

    for (int chunk = 0; chunk < KCODES / NC; ++chunk) {
        float acc[8][8];
        #pragma unroll
        for (int m = 0; m < 8; ++m)
            #pragma unroll
            for (int n = 0; n < 8; ++n) acc[m][n] = 0.f;

        for (int ks = 0; ks < HID / KS; ++ks) {
            __syncthreads();
            #pragma unroll
            for (int i = 0; i < 4; ++i) {
                int f   = tid + i * 256;
                int row = f >> 3;
                int k4  = f & 7;
                float4 zv = z4g[(tokBase + row) * (HID / 4) + ks * (KS / 4) + k4];
                int b = row * PAD + k4 * 4;
                zs[b + 0] = zv.x; zs[b + 1] = zv.y; zs[b + 2] = zv.z; zs[b + 3] = zv.w;
                float4 cv = cb4g[(chunk * NC + row) * (HID / 4) + ks * (KS / 4) + k4];
                cs[b + 0] = cv.x; cs[b + 1] = cv.y; cs[b + 2] = cv.z; cs[b + 3] = cv.w;
            }
            __syncthreads();

            #pragma unroll 2
            for (int k = 0; k < KS; ++k) {
                float zf[8], cf[8];
                #pragma unroll
                for (int m = 0; m < 8; ++m) zf[m] = zs[(ty * 8 + m) * PAD + k];
                #pragma unroll
                for (int n = 0; n < 8; ++n) cf[n] = cs[(tx * 8 + n) * PAD + k];
                #pragma unroll
                for (int m = 0; m < 8; ++m)
                    #pragma unroll
                    for (int n = 0; n < 8; ++n)
                        acc[m][n] = fmaf(zf[m], cf[n], acc[m][n]);
            }
        }

        #pragma unroll
        for (int n = 0; n < 8; ++n) {
            int code = chunk * NC + tx * 8 + n;
            float c2v = c2g[code];
            #pragma unroll
            for (int m = 0; m < 8; ++m) {
                float s = fmaf(-2.f, acc[m][n], c2v);
                if (s < bs[m]) { bs2[m] = bs[m]; bs[m] = s; bi[m] = code; }
                else if (s < bs2[m]) bs2[m] = s;
            }
        }
    }

    __syncthreads();
    float* rs   = smem;
    int*   ri   = reinterpret_cast<int*>(smem + BM * 16);
    float* rs2  = smem + BM * 32;
    int*   inds = reinterpret_cast<int*>(smem + BM * 48);
    float* wred = smem + BM * 48 + BM;

    #pragma unroll
    for (int m = 0; m < 8; ++m) {
        int tok = ty * 8 + m;
        rs [tok * 16 + tx] = bs[m];
        ri [tok * 16 + tx] = bi[m];
        rs2[tok * 16 + tx] = bs2[m];
    }
    __syncthreads();

    if (tid < BM) {
        float B1 = rs[tid * 16];
        int   I1 = ri[tid * 16];
        float B2 = rs2[tid * 16];
        for (int j = 1; j < 16; ++j) {
            float b1v = rs [tid * 16 + j];
            int   i1v = ri [tid * 16 + j];
            float b2v = rs2[tid * 16 + j];
            if (b1v < B1 || (b1v == B1 && i1v < I1)) {
                B2 = fminf(B1, b2v); B1 = b1v; I1 = i1v;
            } else {
                B2 = fminf(B2, b1v);
            }
        }
        inds[tid] = I1;
        out[IND_OFF + tokBase + tid] = (float)I1;
        if (B2 - B1 <= TAU) {
            int pos = atomicAdd(cnt, 1);
            if (pos < cap) list[pos] = tokBase + tid;
        }
    }
    __syncthreads();

    float loc = 0.f;
    float4* out4 = reinterpret_cast<float4*>(out);
    for (int it = 0; it < (BM * HID / 4) / 256; ++it) {
        int e4  = it * 256 + tid;
        int tok = e4 >> 6;
        int h4  = e4 & 63;
        int code = inds[tok];
        float4 cv = cb4g[code * 64 + h4];
        float4 zv = z4g[(tokBase + tok) * 64 + h4];
        out4[(tokBase + tok) * 64 + h4] = cv;
        float dx = cv.x - zv.x, dy = cv.y - zv.y;
        float dz = cv.z - zv.z, dw = cv.w - zv.w;
        loc = fmaf(dx, dx, loc);
        loc = fmaf(dy, dy, loc);
        loc = fmaf(dz, dz, loc);
        loc = fmaf(dw, dw, loc);
    }
    #pragma unroll
    for (int off = 32; off > 0; off >>= 1) loc += __shfl_xor(loc, off, 64);
    int wave = tid >> 6;
    if ((tid & 63) == 0) wred[wave] = loc;
    __syncthreads();
    if (tid == 0) {
        double t = (double)wred[0] + (double)wred[1] +
                   (double)wred[2] + (double)wred[3];
        atomicAdd(loss_acc, t);
    }
}

// ---------------------------------------------------------------------------
// refine: re-score flagged tokens with the EMULATED reference f32 pipeline:
//   D_k = fl32( fl32(z2 - fl32(2*cross_k)) + c2_k ),  argmin first-index.
// cross in f64 (any summation order: f64 error ~1e-13 << f32 ulp), computed
// with float4 loads + 8 independent partial chains for ILP.
// Also finalizes the loss output (block 0, thread 0).
// ---------------------------------------------------------------------------
__global__ __launch_bounds__(256) void vq_refine(
    const float* __restrict__ z, const float* __restrict__ cb,
    const float* __restrict__ c2g, const double* __restrict__ loss_acc,
    const int* __restrict__ cnt, const int* __restrict__ list,
    float* __restrict__ out, int cap) {

    if (blockIdx.x == 0 && threadIdx.x == 0)
        out[LOSS_OFF] = (float)(2.0 * (*loss_acc) / (double)(M_TOKENS * HID));

    __shared__ float  zrow[HID];
    __shared__ double red_d[256];
    __shared__ int    red_i[256];

    const int tid = threadIdx.x;
    int n = *cnt; if (n > cap) n = cap;

    for (int idx = blockIdx.x; idx < n; idx += gridDim.x) {
        int t = list[idx];
        float zi = z[t * HID + tid];
        zrow[tid] = zi;
        red_d[tid] = (double)zi * (double)zi;
        __syncthreads();
        for (int s = 128; s > 0; s >>= 1) {
            if (tid < s) red_d[tid] += red_d[tid + s];
            __syncthreads();
        }
        float z2f = (float)red_d[0];
        __syncthreads();

        // two codes per thread: k=tid and k=tid+256; 8 f64 chains of 64
        const float4* zr4 = reinterpret_cast<const float4*>(zrow);
        const float4* c0  = reinterpret_cast<const float4*>(cb + tid * HID);
        const float4* c1  = reinterpret_cast<const float4*>(cb + (tid + 256) * HID);
        double p00 = 0, p01 = 0, p02 = 0, p03 = 0;
        double p10 = 0, p11 = 0, p12 = 0, p13 = 0;
        #pragma unroll 4
        for (int i = 0; i < HID / 4; ++i) {
            float4 zv = zr4[i];
            float4 a = c0[i];
            float4 b = c1[i];
            p00 = fma((double)zv.x, (double)a.x, p00);
            p01 = fma((double)zv.y, (double)a.y, p01);
            p02 = fma((double)zv.z, (double)a.z, p02);
            p03 = fma((double)zv.w, (double)a.w, p03);
            p10 = fma((double)zv.x, (double)b.x, p10);
            p11 = fma((double)zv.y, (double)b.y, p11);
            p12 = fma((double)zv.z, (double)b.z, p12);
            p13 = fma((double)zv.w, (double)b.w, p13);
        }
        double bestD = 1e300; int bestK = 1 << 30;
        #pragma unroll
        for (int c = 0; c < 2; ++c) {
            int k = tid + c * 256;
            double accd = (c == 0) ? ((p00 + p01) + (p02 + p03))
                                   : ((p10 + p11) + (p12 + p13));
            float cross32 = (float)accd;                      // fl32(cross)
            float u = 2.0f * cross32;                          // exact
            float tq = (float)((double)z2f - (double)u);       // fl32(z2-u)
            double v = (double)tq + (double)c2g[k];
            float D = (float)v;                                // fl32(t+c2)
            double Dd = (double)D;
            if (Dd < bestD || (Dd == bestD && k < bestK)) { bestD = Dd; bestK = k; }
        }
        red_d[tid] = bestD; red_i[tid] = bestK;
        __syncthreads();
        for (int s = 128; s > 0; s >>= 1) {
            if (tid < s) {
                double d2 = red_d[tid + s]; int i2 = red_i[tid + s];
                if (d2 < red_d[tid] || (d2 == red_d[tid] && i2 < red_i[tid])) {
                    red_d[tid] = d2; red_i[tid] = i2;
                }
            }
            __syncthreads();
        }
        int best = red_i[0];
        if (tid == 0) out[IND_OFF + t] = (float)best;
        out[t * HID + tid] = cb[best * HID + tid];
        __syncthreads();
    }
}

extern "C" void kernel_launch(void* const* d_in, const int* in_sizes, int n_in,
                              void* d_out, int out_size, void* d_ws, size_t ws_size,
                              hipStream_t stream) {
    const float* z  = (const float*)d_in[0];
    const float* cb = (const float*)d_in[1];
    float* out = (float*)d_out;
    double* acc = (double*)d_ws;
    int*  cnt = (int*)((char*)d_ws + 8);
    float* c2 = (float*)((char*)d_ws + WS_C2_OFF);

    if (ws_size >= WS_MIN_FAST) {
        unsigned short* Bhi = (unsigned short*)((char*)d_ws + WS_BHI_OFF);
        unsigned short* Blo = (unsigned short*)((char*)d_ws + WS_BLO_OFF);
        int* list = (int*)((char*)d_ws + WS_LIST_OFF_FAST);
        int cap = 8192;
        vq_prep<<<66, 256, 0, stream>>>(cb, Bhi, Blo, c2, acc, cnt);
        vq_main_mfma<<<M_TOKENS / 128, 256, 0, stream>>>(
            z, cb, c2, Bhi, Blo, out, acc, cnt, list, cap);
        vq_refine<<<256, 256, 0, stream>>>(z, cb, c2, acc, cnt, list, out, cap);
    } else {
        int* list = (int*)((char*)d_ws + WS_LIST_OFF_SLOW);
        int cap = 0;
        if (ws_size > WS_LIST_OFF_SLOW + 16) {
            size_t avail = (ws_size - WS_LIST_OFF_SLOW) / 4;
            cap = (avail > 8192) ? 8192 : (int)avail;
        }
        vq_init<<<1, 512, 0, stream>>>(cb, c2, acc, cnt);
        vq_main_f32<<<M_TOKENS / BM, 256, 0, stream>>>(
            z, cb, c2, out, acc, cnt, list, cap);
        vq_refine<<<256, 256, 0, stream>>>(z, cb, c2, acc, cnt, list, out, cap);
    }
}